// Round 9
// baseline (3070.627 us; speedup 1.0000x reference)
//
#include <hip/hip_runtime.h>
#include <hip/hip_bf16.h>

// MoE expert MLP: y[b] = (gelu(x[b] @ W1[e] + b1[e]) @ W2[e] + b2[e]) * w[b]
// B=8, S=4096, D=1024, F=4096, E=8. f32 in/out; bf16 MFMA 16x16x32, 256^2 tile.
// R9: register-pipelined K-loop — read tile t+1's fragments during tile t's
// MFMAs (independent ops, compiler interleaves); burst-stage t+2 at tile
// start; ONE lgkmcnt(0)+vmcnt(0)+barrier per tile. No mid-tile fences.

#define B_ 8
#define S_ 4096
#define D_ 1024
#define F_ 4096
#define E_ 8

typedef __bf16 bf16x8 __attribute__((ext_vector_type(8)));
typedef float f32x4 __attribute__((ext_vector_type(4)));

__device__ __forceinline__ unsigned short f2bf(float f) {
  unsigned u = __float_as_uint(f);
  u += 0x7FFFu + ((u >> 16) & 1u);   // round-to-nearest-even
  return (unsigned short)(u >> 16);
}

#define GLD16(g, l) __builtin_amdgcn_global_load_lds(                         \
    (const __attribute__((address_space(1))) unsigned int*)(g),              \
    (__attribute__((address_space(3))) unsigned int*)(l), 16, 0, 0)

// ---------------------------------------------------------------------------
// Transpose + f32->bf16:  src (nmat, R, C) f32  ->  dst (nmat, C, R) bf16
// ---------------------------------------------------------------------------
__global__ __launch_bounds__(256) void transpose_cvt_kernel(
    const float* __restrict__ src, unsigned short* __restrict__ dst,
    int R, int C) {
  __shared__ float t[32][33];
  const float* s = src + (size_t)blockIdx.z * R * C;
  unsigned short* d = dst + (size_t)blockIdx.z * R * C;
  int c0 = blockIdx.x * 32, r0 = blockIdx.y * 32;
  int x = threadIdx.x, y = threadIdx.y;      // 32 x 8
#pragma unroll
  for (int j = 0; j < 32; j += 8)
    t[y + j][x] = s[(size_t)(r0 + y + j) * C + (c0 + x)];
  __syncthreads();
#pragma unroll
  for (int j = 0; j < 32; j += 8)
    d[(size_t)(c0 + y + j) * R + (r0 + x)] = f2bf(t[x][y + j]);
}

// ---------------------------------------------------------------------------
// f32 -> bf16 flat convert, vectorized
// ---------------------------------------------------------------------------
__global__ __launch_bounds__(256) void cvt_bf16_kernel(
    const float* __restrict__ src, unsigned short* __restrict__ dst, long n4) {
  long i = (long)blockIdx.x * 256 + threadIdx.x;
  long stride = (long)gridDim.x * 256;
  for (; i < n4; i += stride) {
    float4 v = ((const float4*)src)[i];
    uint2 o;
    o.x = (unsigned)f2bf(v.x) | ((unsigned)f2bf(v.y) << 16);
    o.y = (unsigned)f2bf(v.z) | ((unsigned)f2bf(v.w) << 16);
    ((uint2*)dst)[i] = o;
  }
}

// ---------------------------------------------------------------------------
// 256x256-tile GEMM, register-pipelined (R9).
//   8 waves (2M x 4N), per-wave 128x64 output, BK=64, mfma 16x16x32 bf16.
//   LDS 128 KiB: buf{0,1} x { A[2 halves 128x64] , B[2 halves 128x64] },
//   16B-chunk XOR swizzle: chunk cc of row r holds global k-chunk cc^(r&7)
//   (0 conflicts at the 16x16 read pattern, verified R5).
//   Steady-state tile t (even->setA/bufs as coded, odd mirrored):
//     burst-issue 8 gload_lds (tile t+2 -> buf[t&1]);   // full-tile slack
//     24 ds_read_b128 (tile t+1 frags, buf[(t+1)&1] -> other reg set);
//     64 MFMA on current reg set (INDEPENDENT of the reads -> compiler
//       interleaves; no mid-tile barriers/fences);
//     lgkmcnt(0); vmcnt(0); s_barrier.                  // one sync per tile
//   Safety: burst targets buf[t&1], whose data (tile t) was consumed into
//   registers during tile t-1 and lgkm-drained before t-1's end barrier;
//   reads target buf[(t+1)&1], fully landed (vmcnt(0) at t-1's end).
// ---------------------------------------------------------------------------

#define STAGE(cur, op, h, tk, base)                                           \
  {                                                                           \
    const unsigned short* g0_ = (base) + (size_t)((h) * 128 + sr) * LDK +     \
                                (tk) * 64 + sgc * 8;                          \
    GLD16(g0_, smem + (cur) * 65536 + (op) * 32768 + (h) * 16384 +            \
                   wave * 1024);                                              \
    GLD16(g0_ + (size_t)64 * LDK,                                             \
          smem + (cur) * 65536 + (op) * 32768 + (h) * 16384 + 8192 +          \
              wave * 1024);                                                   \
  }

#define BURST(cur, tk)                                                        \
  STAGE(cur, 0, 0, tk, Abase);                                                \
  STAGE(cur, 0, 1, tk, Abase);                                                \
  STAGE(cur, 1, 0, tk, Bbase);                                                \
  STAGE(cur, 1, 1, tk, Bbase);

// read all 24 fragments of one K-tile into a register set
#define READSET(cur, aS, b0S, b1S)                                            \
  _Pragma("unroll") for (int m = 0; m < 4; ++m) {                             \
    const char* pa0_ =                                                        \
        smem + (cur) * 65536 + (wr * 64 + m * 16 + l15) * 128;                \
    aS[m][0] = *(const bf16x8*)(pa0_ + ca0);                                  \
    aS[m][1] = *(const bf16x8*)(pa0_ + ca1);                                  \
    const char* pa1_ = pa0_ + 16384;                                          \
    aS[4 + m][0] = *(const bf16x8*)(pa1_ + ca0);                              \
    aS[4 + m][1] = *(const bf16x8*)(pa1_ + ca1);                              \
  }                                                                           \
  _Pragma("unroll") for (int n = 0; n < 2; ++n) {                             \
    const char* pb0_ =                                                        \
        smem + (cur) * 65536 + 32768 + (wc * 32 + n * 16 + l15) * 128;        \
    b0S[n][0] = *(const bf16x8*)(pb0_ + ca0);                                 \
    b0S[n][1] = *(const bf16x8*)(pb0_ + ca1);                                 \
    const char* pb1_ = pb0_ + 16384;                                          \
    b1S[n][0] = *(const bf16x8*)(pb1_ + ca0);                                 \
    b1S[n][1] = *(const bf16x8*)(pb1_ + ca1);                                 \
  }

// 64 MFMA on a register set
#define MFMASET(aS, b0S, b1S)                                                 \
  _Pragma("unroll") for (int ks = 0; ks < 2; ++ks)                            \
      _Pragma("unroll") for (int m = 0; m < 8; ++m)                           \
          _Pragma("unroll") for (int n = 0; n < 2; ++n) {                     \
    acc[m][n] = __builtin_amdgcn_mfma_f32_16x16x32_bf16(                      \
        aS[m][ks], b0S[n][ks], acc[m][n], 0, 0, 0);                           \
    acc[m][n + 2] = __builtin_amdgcn_mfma_f32_16x16x32_bf16(                  \
        aS[m][ks], b1S[n][ks], acc[m][n + 2], 0, 0, 0);                       \
  }

#define TILE_SYNC                                                             \
  asm volatile("s_waitcnt lgkmcnt(0)" ::: "memory");                          \
  asm volatile("s_waitcnt vmcnt(0)" ::: "memory");                            \
  __builtin_amdgcn_s_barrier();

template <int NT, int LDK, int NCOL, bool GELU>
__global__ __launch_bounds__(512, 2) void gemmrp_kernel(
    const unsigned short* __restrict__ A,   // [rows][LDK] bf16 (chunk-local)
    const unsigned short* __restrict__ Bw,  // [E][NCOL][LDK] bf16
    const float* __restrict__ bias,         // [E][NCOL]
    const int* __restrict__ eidx, const float* __restrict__ ew,
    void* __restrict__ Out, int grow0, int nbm) {
  extern __shared__ __align__(16) char smem[];

  const int tid = threadIdx.x;
  const int lane = tid & 63;
  const int wave = tid >> 6;
  const int wr = wave >> 2;         // 0..1 (M)
  const int wc = wave & 3;          // 0..3 (N)
  const int l15 = lane & 15, lhi = lane >> 4;

  const int nwg = nbm * (NCOL / 256);
  int wg = blockIdx.x;
  if ((nwg & 7) == 0) wg = (wg & 7) * (nwg >> 3) + (wg >> 3);  // XCD swizzle
  const int bm = wg % nbm, bn = wg / nbm;

  const int bat = (grow0 + bm * 256) >> 12;
  const int e = eidx[bat];

  const unsigned short* Abase = A + (size_t)bm * 256 * LDK;
  const unsigned short* Bbase =
      Bw + (size_t)e * (F_ * D_) + (size_t)bn * 256 * LDK;

  // staging per-thread constants (swizzled source)
  const int sr = tid >> 3;                  // 0..63 (row within 64-row slab)
  const int sgc = (tid & 7) ^ (sr & 7);     // global 16B chunk for lds chunk
  // ds_read per-thread swizzled chunk offsets (row&7 == l15&7 always)
  const int ca0 = ((lhi ^ (l15 & 7)) << 4);
  const int ca1 = (((4 + lhi) ^ (l15 & 7)) << 4);

  f32x4 acc[8][4] = {};
  bf16x8 aA[8][2], b0A[2][2], b1A[2][2];    // register set A (even tiles)
  bf16x8 aB[8][2], b0B[2][2], b1B[2][2];    // register set B (odd tiles)

  // prologue: burst t0 -> buf0, t1 -> buf1; read t0 frags into set A
  BURST(0, 0);
  BURST(1, 1);
  asm volatile("s_waitcnt vmcnt(8)" ::: "memory");   // t0's 8 loads landed
  __builtin_amdgcn_s_barrier();
  READSET(0, aA, b0A, b1A);                          // t0 -> set A
  TILE_SYNC;                                         // reads drained, t1 landed

#pragma unroll 1
  for (int t = 0; t < NT; t += 2) {
    // even tile t: MFMA set A, read t+1 (buf1) into set B, burst t+2 -> buf0
    if (t + 2 < NT) { BURST(0, t + 2); }
    if (t + 1 < NT) { READSET(1, aB, b0B, b1B); }
    MFMASET(aA, b0A, b1A);
    TILE_SYNC;
    // odd tile t+1: MFMA set B, read t+2 (buf0) into set A, burst t+3 -> buf1
    if (t + 3 < NT) { BURST(1, t + 3); }
    if (t + 2 < NT) { READSET(0, aA, b0A, b1A); }
    MFMASET(aB, b0B, b1B);
    TILE_SYNC;
  }

  if (GELU) {
    // --- coalesced bf16 epilogue through LDS (K-loop smem is dead) ---
    unsigned short* cs = (unsigned short*)smem;  // C-tile [256][256] bf16
#pragma unroll
    for (int n = 0; n < 4; ++n) {
      const int tcol =
          (n < 2 ? wc * 32 + n * 16 : 128 + wc * 32 + (n - 2) * 16) + l15;
      const float bv = bias[(size_t)e * NCOL + bn * 256 + tcol];
#pragma unroll
      for (int m = 0; m < 8; ++m) {
        const int trow =
            (m < 4 ? wr * 64 + m * 16 : 128 + wr * 64 + (m - 4) * 16) +
            lhi * 4;
#pragma unroll
        for (int r = 0; r < 4; ++r) {
          float v = acc[m][n][r] + bv;
          // tanh-form gelu: v * sigmoid(2 * 0.79788456*(v + 0.044715 v^3))
          float zz = v * (0.79788456080286536f + 0.0356774081f * v * v);
          float g = v / (1.0f + __expf(-2.0f * zz));
          cs[(trow + r) * 256 + tcol] = f2bf(g);
        }
      }
    }
    __builtin_amdgcn_s_barrier();
    unsigned short* Ho = (unsigned short*)Out + (size_t)bm * 256 * NCOL +
                         (size_t)bn * 256;
    const int rsub = tid >> 5, cc = tid & 31;
#pragma unroll
    for (int it = 0; it < 16; ++it) {
      const int row = it * 16 + rsub;
      *(uint4*)(Ho + (size_t)row * NCOL + cc * 8) =
          *(const uint4*)(smem + row * 512 + cc * 16);
    }
  } else {
    // f32 output: 16 lanes x 4B = 64B contiguous segments
    const float scale = ew[bat];
#pragma unroll
    for (int n = 0; n < 4; ++n) {
      const int tcol =
          (n < 2 ? wc * 32 + n * 16 : 128 + wc * 32 + (n - 2) * 16) + l15;
      const int col = bn * 256 + tcol;
      const float bv = bias[(size_t)e * NCOL + col];
#pragma unroll
      for (int m = 0; m < 8; ++m) {
        const int trow =
            (m < 4 ? wr * 64 + m * 16 : 128 + wr * 64 + (m - 4) * 16) +
            lhi * 4;
        const size_t rowb = (size_t)bm * 256 + trow;
#pragma unroll
        for (int r = 0; r < 4; ++r)
          ((float*)Out)[(rowb + r) * NCOL + col] = (acc[m][n][r] + bv) * scale;
      }
    }
  }
}

// ---------------------------------------------------------------------------
extern "C" void kernel_launch(void* const* d_in, const int* in_sizes, int n_in,
                              void* d_out, int out_size, void* d_ws,
                              size_t ws_size, hipStream_t stream) {
  const float* x = (const float*)d_in[0];
  const float* ew = (const float*)d_in[1];
  const float* W1 = (const float*)d_in[2];
  const float* b1 = (const float*)d_in[3];
  const float* W2 = (const float*)d_in[4];
  const float* b2 = (const float*)d_in[5];
  const int* eidx = (const int*)d_in[6];
  float* out = (float*)d_out;

  char* ws = (char*)d_ws;
  const size_t WT = (size_t)E_ * F_ * D_ * 2;  // 64 MiB per transposed weight
  const size_t XB = (size_t)B_ * S_ * D_ * 2;  // 64 MiB bf16 x
  unsigned short* w1t = (unsigned short*)ws;
  unsigned short* w2t = (unsigned short*)(ws + WT);

  auto g1 = gemmrp_kernel<16, D_, F_, true>;
  auto g2 = gemmrp_kernel<64, F_, D_, false>;
  hipFuncSetAttribute((const void*)g1,
                      hipFuncAttributeMaxDynamicSharedMemorySize, 131072);
  hipFuncSetAttribute((const void*)g2,
                      hipFuncAttributeMaxDynamicSharedMemorySize, 131072);

  // weights: W1 (E,D,F)->(E,F,D), W2 (E,F,D)->(E,D,F), bf16
  transpose_cvt_kernel<<<dim3(F_ / 32, D_ / 32, E_), dim3(32, 8), 0, stream>>>(
      W1, w1t, D_, F_);
  transpose_cvt_kernel<<<dim3(D_ / 32, F_ / 32, E_), dim3(32, 8), 0, stream>>>(
      W2, w2t, F_, D_);

  const long total_rows = (long)B_ * S_;  // 32768

  // full xbf + hbuf chunked at <=16384 rows so H stays L3-resident
  long avail = (long)ws_size - (long)(2 * WT + XB);
  long CH = avail > 0 ? (avail / ((long)F_ * 2)) : 0;
  CH = (CH / 256) * 256;
  if (CH > 16384) CH = 16384;
  if (CH > total_rows) CH = total_rows;

  if (CH >= 256) {
    unsigned short* xbf = (unsigned short*)(ws + 2 * WT);
    unsigned short* hbuf = (unsigned short*)(ws + 2 * WT + XB);
    cvt_bf16_kernel<<<2048, 256, 0, stream>>>(x, xbf, (long)B_ * S_ * D_ / 4);
    for (long r0 = 0; r0 < total_rows; r0 += CH) {
      long nr = total_rows - r0;
      if (nr > CH) nr = CH;
      int nbm = (int)(nr / 256);
      g1<<<dim3(nbm * (F_ / 256)), 512, 131072, stream>>>(
          xbf + r0 * D_, w1t, b1, eidx, ew, hbuf, (int)r0, nbm);
      g2<<<dim3(nbm * (D_ / 256)), 512, 131072, stream>>>(
          hbuf, w2t, b2, eidx, ew, out + r0 * D_, (int)r0, nbm);
    }
  } else {
    // tiny-ws fallback: chunk xbf and hbuf together
    long cap = ((long)ws_size - (long)(2 * WT)) / ((long)(D_ + F_) * 2);
    long chunk = (cap / 256) * 256;
    if (chunk > total_rows) chunk = total_rows;
    if (chunk < 256) chunk = 256;
    unsigned short* xbf = (unsigned short*)(ws + 2 * WT);
    unsigned short* hbuf = xbf + (size_t)chunk * D_;
    for (long r0 = 0; r0 < total_rows; r0 += chunk) {
      long nr = total_rows - r0;
      if (nr > chunk) nr = chunk;
      cvt_bf16_kernel<<<512, 256, 0, stream>>>(x + r0 * D_, xbf, nr * D_ / 4);
      int nbm = (int)(nr / 256);
      g1<<<dim3(nbm * (F_ / 256)), 512, 131072, stream>>>(
          xbf, w1t, b1, eidx, ew, hbuf, (int)r0, nbm);
      g2<<<dim3(nbm * (D_ / 256)), 512, 131072, stream>>>(
          hbuf, w2t, b2, eidx, ew, out + r0 * D_, (int)r0, nbm);
    }
  }
}

// Round 10
// 663.248 us; speedup vs baseline: 4.6297x; 4.6297x over previous
//
#include <hip/hip_runtime.h>
#include <hip/hip_bf16.h>

// MoE expert MLP: y[b] = (gelu(x[b] @ W1[e] + b1[e]) @ W2[e] + b2[e]) * w[b]
// B=8, S=4096, D=1024, F=4096, E=8. f32 in/out; bf16 MFMA 16x16x32, 256^2 tile.
// R10 = R8 inner loop (R5 4-phase, best measured) + contiguous 64-col wave
// stripes so the epilogue writes full 128B lines directly (no LDS roundtrip).

#define B_ 8
#define S_ 4096
#define D_ 1024
#define F_ 4096
#define E_ 8

typedef __bf16 bf16x8 __attribute__((ext_vector_type(8)));
typedef float f32x4 __attribute__((ext_vector_type(4)));

__device__ __forceinline__ unsigned short f2bf(float f) {
  unsigned u = __float_as_uint(f);
  u += 0x7FFFu + ((u >> 16) & 1u);   // round-to-nearest-even
  return (unsigned short)(u >> 16);
}

#define GLD16(g, l) __builtin_amdgcn_global_load_lds(                         \
    (const __attribute__((address_space(1))) unsigned int*)(g),              \
    (__attribute__((address_space(3))) unsigned int*)(l), 16, 0, 0)

// ---------------------------------------------------------------------------
// Transpose + f32->bf16:  src (nmat, R, C) f32  ->  dst (nmat, C, R) bf16
// ---------------------------------------------------------------------------
__global__ __launch_bounds__(256) void transpose_cvt_kernel(
    const float* __restrict__ src, unsigned short* __restrict__ dst,
    int R, int C) {
  __shared__ float t[32][33];
  const float* s = src + (size_t)blockIdx.z * R * C;
  unsigned short* d = dst + (size_t)blockIdx.z * R * C;
  int c0 = blockIdx.x * 32, r0 = blockIdx.y * 32;
  int x = threadIdx.x, y = threadIdx.y;      // 32 x 8
#pragma unroll
  for (int j = 0; j < 32; j += 8)
    t[y + j][x] = s[(size_t)(r0 + y + j) * C + (c0 + x)];
  __syncthreads();
#pragma unroll
  for (int j = 0; j < 32; j += 8)
    d[(size_t)(c0 + y + j) * R + (r0 + x)] = f2bf(t[x][y + j]);
}

// ---------------------------------------------------------------------------
// f32 -> bf16 flat convert, vectorized
// ---------------------------------------------------------------------------
__global__ __launch_bounds__(256) void cvt_bf16_kernel(
    const float* __restrict__ src, unsigned short* __restrict__ dst, long n4) {
  long i = (long)blockIdx.x * 256 + threadIdx.x;
  long stride = (long)gridDim.x * 256;
  for (; i < n4; i += stride) {
    float4 v = ((const float4*)src)[i];
    uint2 o;
    o.x = (unsigned)f2bf(v.x) | ((unsigned)f2bf(v.y) << 16);
    o.y = (unsigned)f2bf(v.z) | ((unsigned)f2bf(v.w) << 16);
    ((uint2*)dst)[i] = o;
  }
}

// ---------------------------------------------------------------------------
// 256x256-tile 4-phase GEMM (R5 schedule; R10 column mapping).
//   8 waves (2M x 4N): wave owns rows [wr*128-ish split] x ONE contiguous
//   64-col stripe: col = (wc>>1)*128 + (wc&1)*64 + n*16 + l15, n=0..3 —
//   all four B-frag rows come from a single B-half (bhalf = wc>>1).
//   Reads: Ah0@ph1 (8), b01@ph1 (4), b23@ph2 (4), Ah1@ph3 (8).
//   Retirement: Ah0 after ph1; both B-halves after ph2; Ah1 after ph3.
//   Stages (per tile t): ph1 Ah1(t+1)->buf^1, ph2 Ah0(t+2), ph3 Bh0(t+2),
//   ph4 Bh1(t+2); vmcnt(6) only at ph4 (3 half-tiles in flight). All stage
//   targets are barrier-separated from their last readers (as in R5/R8).
//   Epilogue: per (m,r) the 4 n-stores are consecutive and cover one full
//   128B line (bf16) / two full lines (f32) -> direct global stores, no RMW,
//   no LDS roundtrip, no bank conflicts.
// ---------------------------------------------------------------------------

#define STAGE(cur, op, h, tk, base)                                           \
  {                                                                           \
    const unsigned short* g0_ = (base) + (size_t)((h) * 128 + sr) * LDK +     \
                                (tk) * 64 + sgc * 8;                          \
    GLD16(g0_, smem + (cur) * 65536 + (op) * 32768 + (h) * 16384 +            \
                   wave * 1024);                                              \
    GLD16(g0_ + (size_t)64 * LDK,                                             \
          smem + (cur) * 65536 + (op) * 32768 + (h) * 16384 + 8192 +          \
              wave * 1024);                                                   \
  }

#define LDA_HALF(cur, H)                                                      \
  _Pragma("unroll") for (int m = 0; m < 4; ++m) {                             \
    const char* p_ = smem + (cur) * 65536 + (H) * 16384 +                     \
                     (wr * 64 + m * 16 + l15) * 128;                          \
    aM[m][0] = *(const bf16x8*)(p_ + ca0);                                    \
    aM[m][1] = *(const bf16x8*)(p_ + ca1);                                    \
  }

// B-frags: rows (wc&1)*64 + (Q*2+n)*16 + l15 of half (wc>>1)
#define LDB_Q(cur, Q, breg)                                                   \
  _Pragma("unroll") for (int n = 0; n < 2; ++n) {                             \
    const char* p_ = smem + (cur) * 65536 + 32768 + (wc >> 1) * 16384 +       \
                     ((wc & 1) * 64 + ((Q) * 2 + n) * 16 + l15) * 128;        \
    breg[n][0] = *(const bf16x8*)(p_ + ca0);                                  \
    breg[n][1] = *(const bf16x8*)(p_ + ca1);                                  \
  }

#define MMA_Q(MB, breg, NB)                                                   \
  _Pragma("unroll") for (int ks = 0; ks < 2; ++ks)                            \
      _Pragma("unroll") for (int m = 0; m < 4; ++m)                           \
          _Pragma("unroll") for (int n = 0; n < 2; ++n)                       \
              acc[(MB) + m][(NB) + n] =                                       \
      __builtin_amdgcn_mfma_f32_16x16x32_bf16(                                \
          aM[m][ks], breg[n][ks], acc[(MB) + m][(NB) + n], 0, 0, 0);

#define PH_END                                                                \
  __builtin_amdgcn_s_setprio(0);                                              \
  __builtin_amdgcn_sched_barrier(0);                                          \
  __builtin_amdgcn_s_barrier();

// MODE: 2 = full staging, 1 = tail-1 (stage Ah1 only, drain), 0 = last tile
#define TILE(cur, t, MODE)                                                    \
  LDA_HALF(cur, 0);                                                           \
  LDB_Q(cur, 0, bq0);                                                         \
  if ((MODE) >= 1) STAGE((cur) ^ 1, 0, 1, (t) + 1, Abase);                    \
  __builtin_amdgcn_s_setprio(1);                                              \
  MMA_Q(0, bq0, 0);                                                           \
  PH_END;                                                                     \
  LDB_Q(cur, 1, bq1);                                                         \
  if ((MODE) == 2) STAGE(cur, 0, 0, (t) + 2, Abase);                          \
  __builtin_amdgcn_s_setprio(1);                                              \
  MMA_Q(0, bq1, 2);                                                           \
  PH_END;                                                                     \
  LDA_HALF(cur, 1);                                                           \
  if ((MODE) == 2) STAGE(cur, 1, 0, (t) + 2, Bbase);                          \
  __builtin_amdgcn_s_setprio(1);                                              \
  MMA_Q(4, bq0, 0);                                                           \
  PH_END;                                                                     \
  if ((MODE) == 2) STAGE(cur, 1, 1, (t) + 2, Bbase);                          \
  __builtin_amdgcn_s_setprio(1);                                              \
  MMA_Q(4, bq1, 2);                                                           \
  __builtin_amdgcn_s_setprio(0);                                              \
  __builtin_amdgcn_sched_barrier(0);                                          \
  if ((MODE) == 2) asm volatile("s_waitcnt vmcnt(6)" ::: "memory");           \
  if ((MODE) == 1) asm volatile("s_waitcnt vmcnt(0)" ::: "memory");           \
  __builtin_amdgcn_s_barrier();

template <int NT, int LDK, int NCOL, bool GELU>
__global__ __launch_bounds__(512, 2) void gemm8p_kernel(
    const unsigned short* __restrict__ A,   // [rows][LDK] bf16 (chunk-local)
    const unsigned short* __restrict__ Bw,  // [E][NCOL][LDK] bf16
    const float* __restrict__ bias,         // [E][NCOL]
    const int* __restrict__ eidx, const float* __restrict__ ew,
    void* __restrict__ Out, int grow0, int nbm) {
  extern __shared__ __align__(16) char smem[];

  const int tid = threadIdx.x;
  const int lane = tid & 63;
  const int wave = tid >> 6;
  const int wr = wave >> 2;         // 0..1 (M)
  const int wc = wave & 3;          // 0..3 (N stripe)
  const int l15 = lane & 15, lhi = lane >> 4;

  const int nwg = nbm * (NCOL / 256);
  int wg = blockIdx.x;
  if ((nwg & 7) == 0) wg = (wg & 7) * (nwg >> 3) + (wg >> 3);  // XCD swizzle
  const int bm = wg % nbm, bn = wg / nbm;

  const int bat = (grow0 + bm * 256) >> 12;
  const int e = eidx[bat];

  const unsigned short* Abase = A + (size_t)bm * 256 * LDK;
  const unsigned short* Bbase =
      Bw + (size_t)e * (F_ * D_) + (size_t)bn * 256 * LDK;

  // staging per-thread constants (swizzled source)
  const int sr = tid >> 3;                  // 0..63 (row within 64-row slab)
  const int sgc = (tid & 7) ^ (sr & 7);     // global 16B chunk for lds chunk
  // ds_read per-thread swizzled chunk offsets (row&7 == l15&7 always)
  const int ca0 = ((lhi ^ (l15 & 7)) << 4);
  const int ca1 = (((4 + lhi) ^ (l15 & 7)) << 4);

  f32x4 acc[8][4] = {};
  bf16x8 aM[4][2], bq0[2][2], bq1[2][2];

  // prologue: tile0 all 4 halves, tile1 first 3 (Ah0,Bh0,Bh1)
  STAGE(0, 0, 0, 0, Abase);
  STAGE(0, 1, 0, 0, Bbase);
  STAGE(0, 1, 1, 0, Bbase);
  STAGE(0, 0, 1, 0, Abase);
  STAGE(1, 0, 0, 1, Abase);
  STAGE(1, 1, 0, 1, Bbase);
  STAGE(1, 1, 1, 1, Bbase);
  asm volatile("s_waitcnt vmcnt(6)" ::: "memory");
  __builtin_amdgcn_s_barrier();

#pragma unroll 1
  for (int t = 0; t < NT - 2; t += 2) {
    TILE(0, t, 2);
    TILE(1, t + 1, 2);
  }
  TILE(0, NT - 2, 1);
  TILE(1, NT - 1, 0);

  // ---- direct epilogue: wave owns 64 contiguous cols; per (m,r) the four
  // n-stores are back-to-back on one 128B line (bf16) / two lines (f32) ----
  const int colbase = bn * 256 + (wc >> 1) * 128 + (wc & 1) * 64 + l15;
  float bv[4];
#pragma unroll
  for (int n = 0; n < 4; ++n) bv[n] = bias[(size_t)e * NCOL + colbase + n * 16];
  const float scale = GELU ? 1.0f : ew[bat];

#pragma unroll
  for (int m = 0; m < 8; ++m) {
    const int trow =
        (m < 4 ? wr * 64 + m * 16 : 128 + wr * 64 + (m - 4) * 16) + lhi * 4;
    const size_t rowb = (size_t)bm * 256 + trow;
#pragma unroll
    for (int r = 0; r < 4; ++r) {
      const size_t off = (rowb + r) * NCOL + colbase;
      if (GELU) {
#pragma unroll
        for (int n = 0; n < 4; ++n) {
          float v = acc[m][n][r] + bv[n];
          // tanh-form gelu: v * sigmoid(2 * 0.79788456*(v + 0.044715 v^3))
          float zz = v * (0.79788456080286536f + 0.0356774081f * v * v);
          float g = v / (1.0f + __expf(-2.0f * zz));
          ((unsigned short*)Out)[off + n * 16] = f2bf(g);
        }
      } else {
#pragma unroll
        for (int n = 0; n < 4; ++n)
          ((float*)Out)[off + n * 16] = (acc[m][n][r] + bv[n]) * scale;
      }
    }
  }
}

// ---------------------------------------------------------------------------
extern "C" void kernel_launch(void* const* d_in, const int* in_sizes, int n_in,
                              void* d_out, int out_size, void* d_ws,
                              size_t ws_size, hipStream_t stream) {
  const float* x = (const float*)d_in[0];
  const float* ew = (const float*)d_in[1];
  const float* W1 = (const float*)d_in[2];
  const float* b1 = (const float*)d_in[3];
  const float* W2 = (const float*)d_in[4];
  const float* b2 = (const float*)d_in[5];
  const int* eidx = (const int*)d_in[6];
  float* out = (float*)d_out;

  char* ws = (char*)d_ws;
  const size_t WT = (size_t)E_ * F_ * D_ * 2;  // 64 MiB per transposed weight
  const size_t XB = (size_t)B_ * S_ * D_ * 2;  // 64 MiB bf16 x
  unsigned short* w1t = (unsigned short*)ws;
  unsigned short* w2t = (unsigned short*)(ws + WT);

  auto g1 = gemm8p_kernel<16, D_, F_, true>;
  auto g2 = gemm8p_kernel<64, F_, D_, false>;
  hipFuncSetAttribute((const void*)g1,
                      hipFuncAttributeMaxDynamicSharedMemorySize, 131072);
  hipFuncSetAttribute((const void*)g2,
                      hipFuncAttributeMaxDynamicSharedMemorySize, 131072);

  // weights: W1 (E,D,F)->(E,F,D), W2 (E,F,D)->(E,D,F), bf16
  transpose_cvt_kernel<<<dim3(F_ / 32, D_ / 32, E_), dim3(32, 8), 0, stream>>>(
      W1, w1t, D_, F_);
  transpose_cvt_kernel<<<dim3(D_ / 32, F_ / 32, E_), dim3(32, 8), 0, stream>>>(
      W2, w2t, F_, D_);

  const long total_rows = (long)B_ * S_;  // 32768

  // full xbf + hbuf chunked at <=16384 rows so H stays L3-resident
  long avail = (long)ws_size - (long)(2 * WT + XB);
  long CH = avail > 0 ? (avail / ((long)F_ * 2)) : 0;
  CH = (CH / 256) * 256;
  if (CH > 16384) CH = 16384;
  if (CH > total_rows) CH = total_rows;

  if (CH >= 256) {
    unsigned short* xbf = (unsigned short*)(ws + 2 * WT);
    unsigned short* hbuf = (unsigned short*)(ws + 2 * WT + XB);
    cvt_bf16_kernel<<<2048, 256, 0, stream>>>(x, xbf, (long)B_ * S_ * D_ / 4);
    for (long r0 = 0; r0 < total_rows; r0 += CH) {
      long nr = total_rows - r0;
      if (nr > CH) nr = CH;
      int nbm = (int)(nr / 256);
      g1<<<dim3(nbm * (F_ / 256)), 512, 131072, stream>>>(
          xbf + r0 * D_, w1t, b1, eidx, ew, hbuf, (int)r0, nbm);
      g2<<<dim3(nbm * (D_ / 256)), 512, 131072, stream>>>(
          hbuf, w2t, b2, eidx, ew, out + r0 * D_, (int)r0, nbm);
    }
  } else {
    // tiny-ws fallback: chunk xbf and hbuf together
    long cap = ((long)ws_size - (long)(2 * WT)) / ((long)(D_ + F_) * 2);
    long chunk = (cap / 256) * 256;
    if (chunk > total_rows) chunk = total_rows;
    if (chunk < 256) chunk = 256;
    unsigned short* xbf = (unsigned short*)(ws + 2 * WT);
    unsigned short* hbuf = xbf + (size_t)chunk * D_;
    for (long r0 = 0; r0 < total_rows; r0 += chunk) {
      long nr = total_rows - r0;
      if (nr > chunk) nr = chunk;
      cvt_bf16_kernel<<<512, 256, 0, stream>>>(x + r0 * D_, xbf, nr * D_ / 4);
      int nbm = (int)(nr / 256);
      g1<<<dim3(nbm * (F_ / 256)), 512, 131072, stream>>>(
          xbf, w1t, b1, eidx, ew, hbuf, (int)r0, nbm);
      g2<<<dim3(nbm * (D_ / 256)), 512, 131072, stream>>>(
          hbuf, w2t, b2, eidx, ew, out + r0 * D_, (int)r0, nbm);
    }
  }
}